// Round 4
// baseline (964.192 us; speedup 1.0000x reference)
//
#include <hip/hip_runtime.h>

#define SEQ   32
#define HH    128
#define WW    128
#define CINC  8
#define COUTC 8
#define NG    32      // 4*Cout gates
#define ICH   16      // Cin+Cout
#define TAPS  9
#define ROWS  4       // 2 output rows + halo
#define COLS  130     // 128 + halo

typedef _Float16 half8 __attribute__((ext_vector_type(8)));
typedef _Float16 half4 __attribute__((ext_vector_type(4)));
typedef float floatx16 __attribute__((ext_vector_type(16)));

__device__ __forceinline__ float fast_rcp(float x) { return __builtin_amdgcn_rcpf(x); }
__device__ __forceinline__ float sigmoidf_(float x) {
    return fast_rcp(1.0f + __expf(-x));
}
__device__ __forceinline__ float tanhf_(float x) {
    float e = __expf(-2.0f * x);
    return (1.0f - e) * fast_rcp(1.0f + e);
}

// Wc[g][ic][ky][kx] fp32 -> Wf[tap][gate][ch_half][8ch] f16 (A-operand fragments)
// Also zeroes the 1024 progress flags (workspace is poisoned between runs).
__global__ void prep_weights(const float* __restrict__ Wc, _Float16* __restrict__ Wf,
                             unsigned* __restrict__ flags) {
    int i = blockIdx.x * 256 + threadIdx.x;
    if (i < 1024) flags[i] = 0u;
    if (i >= TAPS * NG * ICH) return;
    int tap = i / (NG * ICH);
    int r   = i % (NG * ICH);
    int g   = r >> 4;
    int ch  = r & 15;
    int half = ch >> 3, c8 = ch & 7;
    int ky = tap / 3, kx = tap % 3;
    float w = Wc[g * (ICH * 9) + ch * 9 + ky * 3 + kx];
    Wf[((tap * NG + g) * 2 + half) * 8 + c8] = (_Float16)w;
}

// ---- X staging: rows 0..3 of half-0 region for timestep tt (no h dependency) ----
__device__ __forceinline__ void stage_X(const float* __restrict__ X, int b, int y0, int tt,
                                        int tid, _Float16* ldsH, _Float16* ldsL) {
#pragma unroll
    for (int i = 0; i < 3; ++i) {
        int idx = tid + i * 256;
        if (idx >= ROWS * COLS) break;
        int col = idx % COLS;
        int row = idx / COLS;
        int gy = y0 + row - 1;
        int gx = col - 1;
        bool inb = ((unsigned)gy < HH) && ((unsigned)gx < WW);
        float v[8];
#pragma unroll
        for (int j = 0; j < 8; ++j)
            v[j] = inb ? X[(((size_t)(b * CINC + j) * SEQ + tt) * HH + gy) * WW + gx] : 0.0f;
        union { half8 h; float4 f; } uh, ul;
#pragma unroll
        for (int j = 0; j < 8; ++j) {
            _Float16 hi = (_Float16)v[j];
            uh.h[j] = hi;
            ul.h[j] = (_Float16)(v[j] - (float)hi);
        }
        *(float4*)&ldsH[(size_t)idx * 8] = uh.f;
        *(float4*)&ldsL[(size_t)idx * 8] = ul.f;
    }
}

// ---- h halo row staging (one wave): reads h(t-1) at global row gy via sc1 loads ----
__device__ __forceinline__ void stage_halo(const float* __restrict__ out, int b, int gy,
                                           int t, int ldsrow, int lane,
                                           _Float16* ldsH, _Float16* ldsL) {
    for (int col = lane; col < COLS; col += 64) {
        int gx = col - 1;
        bool inb = ((unsigned)gy < HH) && ((unsigned)gx < WW);
        float v[8];
#pragma unroll
        for (int j = 0; j < 8; ++j)
            v[j] = inb ? __hip_atomic_load(
                             &out[(((size_t)(b * COUTC + j) * SEQ + (t - 1)) * HH + gy) * WW + gx],
                             __ATOMIC_RELAXED, __HIP_MEMORY_SCOPE_AGENT)
                       : 0.0f;
        union { half8 h; float4 f; } uh, ul;
#pragma unroll
        for (int j = 0; j < 8; ++j) {
            _Float16 hi = (_Float16)v[j];
            uh.h[j] = hi;
            ul.h[j] = (_Float16)(v[j] - (float)hi);
        }
        int item = ROWS * COLS + ldsrow * COLS + col;   // half-1 region
        *(float4*)&ldsH[(size_t)item * 8] = uh.f;
        *(float4*)&ldsL[(size_t)item * 8] = ul.f;
    }
}

template <int T0, int T1>
__device__ __forceinline__ void do_taps(int ry, int x0, int lg, int lh,
                                        const half8* wfrag,
                                        const _Float16* ldsH, const _Float16* ldsL,
                                        floatx16& acc0, floatx16& acc1) {
#pragma unroll
    for (int tap = T0; tap < T1; ++tap) {
        int ky = tap / 3, kx = tap % 3;
        int row = ry + ky;
        int base0 = ((lh * ROWS + row) * COLS + (x0 + lg + kx)) * 8;
        int base1 = base0 + 32 * 8;
        half8 bh0 = *(const half8*)&ldsH[base0];
        half8 bl0 = *(const half8*)&ldsL[base0];
        half8 bh1 = *(const half8*)&ldsH[base1];
        half8 bl1 = *(const half8*)&ldsL[base1];
        acc0 = __builtin_amdgcn_mfma_f32_32x32x16_f16(wfrag[tap], bh0, acc0, 0, 0, 0);
        acc1 = __builtin_amdgcn_mfma_f32_32x32x16_f16(wfrag[tap], bh1, acc1, 0, 0, 0);
        acc0 = __builtin_amdgcn_mfma_f32_32x32x16_f16(wfrag[tap], bl0, acc0, 0, 0, 0);
        acc1 = __builtin_amdgcn_mfma_f32_32x32x16_f16(wfrag[tap], bl1, acc1, 0, 0, 0);
    }
}

// ---------------------------------------------------------------------------
// Fused persistent kernel, neighbor-flag sync, latency-overlapped schedule:
//   phase1: waves 0,1 poll + stage h halo rows; waves 2,3 run their 6
//           neighbor-independent taps   (flag wait hides under MFMA)
//   phase2: remaining taps
//   phase3: epilogue + publish, then X(t+1) prefetch into the dead X region
// Coherence: halo reads / out stores are agent-scope (coherence point);
// publish/poll are atomic RMWs; ordering via __syncthreads vmcnt drain.
// ---------------------------------------------------------------------------
__global__ __launch_bounds__(256, 4) void lstm_fused(
    const float* __restrict__ X,      // (B, Cin, S, H, W)
    const _Float16* __restrict__ Wf,  // (9, 32, 2, 8)
    const float* __restrict__ bc,     // (32,)
    float* __restrict__ out,          // (B, Cout, S, H, W) -- also h history
    unsigned* __restrict__ flags)     // (1024,) steps completed per block
{
    __shared__ __align__(16) _Float16 ldsH[2 * ROWS * COLS * 8];
    __shared__ __align__(16) _Float16 ldsL[2 * ROWS * COLS * 8];

    const int tid = threadIdx.x;
    const int blk = blockIdx.x;
    const int b   = blk >> 6;
    const int yb  = blk & 63;
    const int y0  = yb * 2;

    const int lane = tid & 63;
    const int w    = tid >> 6;       // wave 0..3
    const int lg   = lane & 31;
    const int lh   = lane >> 5;

    const bool hasUp = (yb > 0);
    const bool hasDn = (yb < 63);

    half8 wfrag[TAPS];
#pragma unroll
    for (int tap = 0; tap < TAPS; ++tap)
        wfrag[tap] = *(const half8*)&Wf[((tap * NG + lg) * 2 + lh) * 8];

    float bi[4], bf4[4], bg[4], bo[4];
#pragma unroll
    for (int r = 0; r < 4; ++r) {
        int oc = r + 4 * lh;
        bi[r]  = bc[oc];
        bf4[r] = bc[oc + 8];
        bg[r]  = bc[oc + 16];
        bo[r]  = bc[oc + 24];
    }

    float creg[8];
#pragma unroll
    for (int r = 0; r < 8; ++r) creg[r] = 0.0f;

    const int ry = w >> 1;           // waves 0,1 -> ry=0 ; waves 2,3 -> ry=1
    const int x0 = (w & 1) * 64;
    const int y  = y0 + ry;

    // ---- prologue: zero h region (h(-1)=0), stage X(0) ----
#pragma unroll
    for (int i = 0; i < 3; ++i) {
        int idx = tid + i * 256;
        if (idx >= ROWS * COLS) break;
        int item = ROWS * COLS + idx;
        *(float4*)&ldsH[(size_t)item * 8] = float4{0.f, 0.f, 0.f, 0.f};
        *(float4*)&ldsL[(size_t)item * 8] = float4{0.f, 0.f, 0.f, 0.f};
    }
    stage_X(X, b, y0, 0, tid, ldsH, ldsL);
    __syncthreads();

    for (int t = 0; t < SEQ; ++t) {
        floatx16 acc0, acc1;
#pragma unroll
        for (int r = 0; r < 16; ++r) { acc0[r] = 0.0f; acc1[r] = 0.0f; }

        // ---- phase 1: halo acquisition (waves 0,1) || independent taps (waves 2,3) ----
        if (w == 0) {
            if (t > 0) {
                if (hasUp && lane == 0) {
                    int polls = 0;
                    while (__hip_atomic_fetch_add(&flags[blk - 1], 0u, __ATOMIC_RELAXED,
                                                  __HIP_MEMORY_SCOPE_AGENT) < (unsigned)t
                           && ++polls < (1 << 17))
                        __builtin_amdgcn_s_sleep(1);
                }
                asm volatile("" ::: "memory");   // keep sc1 loads below the spin
                stage_halo(out, b, y0 - 1, t, 0, lane, ldsH, ldsL);
            }
        } else if (w == 1) {
            if (t > 0) {
                if (hasDn && lane == 0) {
                    int polls = 0;
                    while (__hip_atomic_fetch_add(&flags[blk + 1], 0u, __ATOMIC_RELAXED,
                                                  __HIP_MEMORY_SCOPE_AGENT) < (unsigned)t
                           && ++polls < (1 << 17))
                        __builtin_amdgcn_s_sleep(1);
                }
                asm volatile("" ::: "memory");
                stage_halo(out, b, y0 + 2, t, 3, lane, ldsH, ldsL);
            }
        } else {
            // ry==1 waves: taps 0..5 use rows 1,2 (own h + X) only
            do_taps<0, 6>(ry, x0, lg, lh, wfrag, ldsH, ldsL, acc0, acc1);
        }
        __syncthreads();   // halo rows staged

        // ---- phase 2: remaining taps ----
        if (ry == 0)
            do_taps<0, 9>(ry, x0, lg, lh, wfrag, ldsH, ldsL, acc0, acc1);
        else
            do_taps<6, 9>(ry, x0, lg, lh, wfrag, ldsH, ldsL, acc0, acc1);
        __syncthreads();   // all MFMA LDS reads done

        // ---- phase 3: epilogue (gates, c, out stores, h -> LDS rows 1,2) ----
#pragma unroll
        for (int tl = 0; tl < 2; ++tl) {
            floatx16 A = tl ? acc1 : acc0;
            int px = x0 + tl * 32 + lg;
            half4 hh, hl;
#pragma unroll
            for (int r = 0; r < 4; ++r) {
                int oc = r + 4 * lh;
                float zi = A[r]      + bi[r];
                float zf = A[4 + r]  + bf4[r];
                float zg = A[8 + r]  + bg[r];
                float zo = A[12 + r] + bo[r];
                float cp = creg[tl * 4 + r];
                float cn = sigmoidf_(zf) * cp + sigmoidf_(zi) * tanhf_(zg);
                creg[tl * 4 + r] = cn;
                float hval = sigmoidf_(zo) * tanhf_(cn);
                __hip_atomic_store(
                    &out[(((size_t)(b * COUTC + oc) * SEQ + t) * HH + y) * WW + px],
                    hval, __ATOMIC_RELAXED, __HIP_MEMORY_SCOPE_AGENT);
                _Float16 hi = (_Float16)hval;
                hh[r] = hi;
                hl[r] = (_Float16)(hval - (float)hi);
            }
            int hbase = (((1 * ROWS) + 1 + ry) * COLS + (px + 1)) * 8 + 4 * lh;
            *(half4*)&ldsH[hbase] = hh;
            *(half4*)&ldsL[hbase] = hl;
        }

        __syncthreads();   // vmcnt(0) drain per wave: out(t) globally visible
        if (tid == 0 && t + 1 < SEQ)
            __hip_atomic_fetch_add(&flags[blk], 1u,
                                   __ATOMIC_RELAXED, __HIP_MEMORY_SCOPE_AGENT);

        // ---- X(t+1) prefetch into the (now dead) X region; off publish path ----
        if (t + 1 < SEQ)
            stage_X(X, b, y0, t + 1, tid, ldsH, ldsL);
        __syncthreads();   // X(t+1) staged before next phase-1 taps
    }
}

// ---------------------------------------------------------------------------
// Fallback path (proven baseline): one kernel per step, c-state in workspace.
// ---------------------------------------------------------------------------
__global__ __launch_bounds__(256, 4) void step_kernel(
    const float* __restrict__ X,
    const _Float16* __restrict__ Wf,
    const float* __restrict__ bc,
    float* __restrict__ out,
    float* __restrict__ c,
    int t)
{
    __shared__ __align__(16) _Float16 ldsH[2 * ROWS * COLS * 8];
    __shared__ __align__(16) _Float16 ldsL[2 * ROWS * COLS * 8];

    const int tid = threadIdx.x;
    const int b   = blockIdx.x >> 6;
    const int y0  = (blockIdx.x & 63) * 2;

    for (int idx = tid; idx < 2 * ROWS * COLS; idx += 256) {
        int col  = idx % COLS;
        int tmp  = idx / COLS;
        int half = tmp >> 2;
        int row  = tmp & 3;
        int gy = y0 + row - 1;
        int gx = col - 1;
        bool inb = ((unsigned)gy < HH) && ((unsigned)gx < WW);
        float v[8];
#pragma unroll
        for (int j = 0; j < 8; ++j) {
            int ch = half * 8 + j;
            float val = 0.0f;
            if (inb) {
                if (ch < CINC)
                    val = X[(((size_t)(b * CINC + ch) * SEQ + t) * HH + gy) * WW + gx];
                else if (t > 0)
                    val = out[(((size_t)(b * COUTC + (ch - 8)) * SEQ + (t - 1)) * HH + gy) * WW + gx];
            }
            v[j] = val;
        }
        union { half8 h; float4 f; } uh, ul;
#pragma unroll
        for (int j = 0; j < 8; ++j) {
            _Float16 hi = (_Float16)v[j];
            uh.h[j] = hi;
            ul.h[j] = (_Float16)(v[j] - (float)hi);
        }
        *(float4*)&ldsH[(size_t)idx * 8] = uh.f;
        *(float4*)&ldsL[(size_t)idx * 8] = ul.f;
    }

    const int lane = tid & 63;
    const int w    = tid >> 6;
    const int lg   = lane & 31;
    const int lh   = lane >> 5;

    half8 wfrag[TAPS];
#pragma unroll
    for (int tap = 0; tap < TAPS; ++tap)
        wfrag[tap] = *(const half8*)&Wf[((tap * NG + lg) * 2 + lh) * 8];

    __syncthreads();

    const int ry = w >> 1;
    const int x0 = (w & 1) * 64;

    floatx16 acc0, acc1;
#pragma unroll
    for (int r = 0; r < 16; ++r) { acc0[r] = 0.0f; acc1[r] = 0.0f; }

#pragma unroll
    for (int tap = 0; tap < TAPS; ++tap) {
        int ky = tap / 3, kx = tap % 3;
        int row = ry + ky;
        int base0 = ((lh * ROWS + row) * COLS + (x0 + lg + kx)) * 8;
        int base1 = base0 + 32 * 8;
        half8 bh0 = *(const half8*)&ldsH[base0];
        half8 bl0 = *(const half8*)&ldsL[base0];
        half8 bh1 = *(const half8*)&ldsH[base1];
        half8 bl1 = *(const half8*)&ldsL[base1];
        acc0 = __builtin_amdgcn_mfma_f32_32x32x16_f16(wfrag[tap], bh0, acc0, 0, 0, 0);
        acc1 = __builtin_amdgcn_mfma_f32_32x32x16_f16(wfrag[tap], bh1, acc1, 0, 0, 0);
        acc0 = __builtin_amdgcn_mfma_f32_32x32x16_f16(wfrag[tap], bl0, acc0, 0, 0, 0);
        acc1 = __builtin_amdgcn_mfma_f32_32x32x16_f16(wfrag[tap], bl1, acc1, 0, 0, 0);
    }

    const int y = y0 + ry;
#pragma unroll
    for (int tl = 0; tl < 2; ++tl) {
        floatx16 A = tl ? acc1 : acc0;
        int px = x0 + tl * 32 + lg;
#pragma unroll
        for (int r = 0; r < 4; ++r) {
            int oc = r + 4 * lh;
            float zi = A[r]      + bc[oc];
            float zf = A[4 + r]  + bc[oc + 8];
            float zg = A[8 + r]  + bc[oc + 16];
            float zo = A[12 + r] + bc[oc + 24];
            size_t ci = ((size_t)(b * COUTC + oc) * HH + y) * WW + px;
            float cp = (t > 0) ? c[ci] : 0.0f;
            float cn = sigmoidf_(zf) * cp + sigmoidf_(zi) * tanhf_(zg);
            c[ci] = cn;
            out[(((size_t)(b * COUTC + oc) * SEQ + t) * HH + y) * WW + px]
                = sigmoidf_(zo) * tanhf_(cn);
        }
    }
}

extern "C" void kernel_launch(void* const* d_in, const int* in_sizes, int n_in,
                              void* d_out, int out_size, void* d_ws, size_t ws_size,
                              hipStream_t stream) {
    const float* X  = (const float*)d_in[0];
    const float* Wc = (const float*)d_in[1];
    const float* bc = (const float*)d_in[2];
    float* out = (float*)d_out;

    _Float16* Wf    = (_Float16*)d_ws;                        // 9216 B
    unsigned* flags = (unsigned*)((char*)d_ws + 12288);       // 4096 B

    prep_weights<<<18, 256, 0, stream>>>(Wc, Wf, flags);

    void* args[] = { (void*)&X, (void*)&Wf, (void*)&bc, (void*)&out, (void*)&flags };
    hipError_t err = hipLaunchCooperativeKernel((const void*)lstm_fused,
                                                dim3(16 * 64), dim3(256),
                                                args, 0, stream);
    if (err != hipSuccess) {
        // fallback: proven per-step path with c-state in workspace
        float* c = (float*)((char*)d_ws + 16384);
        for (int t = 0; t < SEQ; ++t) {
            step_kernel<<<16 * 64, 256, 0, stream>>>(X, Wf, bc, out, c, t);
        }
    }
}